// Round 1
// baseline (809.043 us; speedup 1.0000x reference)
//
#include <hip/hip_runtime.h>
#include <float.h>
#include <limits.h>
#include <math.h>

namespace {

constexpr int NB = 8;         // batch
constexpr int SL = 2048;      // sequence length L
constexpr int DIM = 128;      // D
constexpr int PP = 64;        // P (projection dim)
constexpr int KK = 64;        // top_k
constexpr int ROWS = 64;      // rows per chunk (strip)
constexpr int CTILE = 32;     // cols per K tile
constexpr int NCHUNK = SL / ROWS;       // 32 chunks per batch
constexpr int TILE_MAX = ROWS * CTILE;  // 2048 = max pushes per tile
constexpr int CAPACITY = TILE_MAX + 576;

__device__ __forceinline__ bool cgt(double v1, int i1, double v2, int i2) {
  // "a ranks before b": larger value, ties broken by smaller flat index
  return (v1 > v2) || (v1 == v2 && i1 < i2);
}

// Select top-KK (descending, ties -> smaller idx) from cval/cidx[0..n).
// Marks winners consumed in place. ov/oi are __shared__ arrays of size KK.
// swv/swi/swp are __shared__ scratch of size 4 (one per wave). blockDim=256.
__device__ void select_topk(double* cval, int* cidx, int n,
                            double* ov, int* oi,
                            double* swv, int* swi, int* swp) {
  const int tid = threadIdx.x;
  for (int k = 0; k < KK; ++k) {
    double bv = -DBL_MAX; int bi = INT_MAX; int bp = -1;
    for (int j = tid; j < n; j += 256) {
      double v = cval[j];
      int ix = cidx[j];
      if (cgt(v, ix, bv, bi)) { bv = v; bi = ix; bp = j; }
    }
    // wave (64-lane) argmax reduce
    for (int off = 32; off > 0; off >>= 1) {
      double v2 = __shfl_down(bv, off);
      int i2 = __shfl_down(bi, off);
      int p2 = __shfl_down(bp, off);
      if (cgt(v2, i2, bv, bi)) { bv = v2; bi = i2; bp = p2; }
    }
    if ((tid & 63) == 0) { int w = tid >> 6; swv[w] = bv; swi[w] = bi; swp[w] = bp; }
    __syncthreads();
    if (tid == 0) {
      double fv = swv[0]; int fi = swi[0]; int fp = swp[0];
      for (int w = 1; w < 4; ++w)
        if (cgt(swv[w], swi[w], fv, fi)) { fv = swv[w]; fi = swi[w]; fp = swp[w]; }
      ov[k] = fv; oi[k] = fi;
      if (fp >= 0) { cval[fp] = -DBL_MAX; cidx[fp] = INT_MAX; }
    }
    __syncthreads();
  }
}

// Canonicalize padding_mask into uint8[NB*SL], robust to the harness passing
// bool as int32 (one word per flag) OR as raw bytes. Detection: in int32
// little-endian 0/1 words, every byte at offset t%4!=0 is zero; in byte mode
// ~half of them are 1.
__global__ __launch_bounds__(256) void mask_canon_kernel(
    const void* __restrict__ mask_raw, unsigned char* __restrict__ vmask) {
  __shared__ int bytemode;
  const unsigned char* bytes = (const unsigned char*)mask_raw;
  if (threadIdx.x == 0) bytemode = 0;
  __syncthreads();
  int local = 0;
  for (int t = threadIdx.x; t < NB * SL; t += 256)
    if ((t & 3) != 0 && bytes[t] != 0) local = 1;
  if (local) atomicOr(&bytemode, 1);
  __syncthreads();
  if (bytemode) {
    for (int t = threadIdx.x; t < NB * SL; t += 256)
      vmask[t] = bytes[t] ? 1 : 0;
  } else {
    const int* words = (const int*)mask_raw;
    for (int t = threadIdx.x; t < NB * SL; t += 256)
      vmask[t] = words[t] ? 1 : 0;
  }
}

// Q = x @ Wq + bq, K = x @ Wk + bk. Double accumulation, fp32 storage.
// 4 rows per block of 256 threads; thread (r = tid>>6, p = tid&63).
__global__ __launch_bounds__(256) void proj_kernel(
    const float* __restrict__ x,
    const float* __restrict__ Wq, const float* __restrict__ bq,
    const float* __restrict__ Wk, const float* __restrict__ bk,
    float* __restrict__ Q, float* __restrict__ K) {
  __shared__ float sx[4][DIM];
  const int row0 = blockIdx.x * 4;
  const int tid = threadIdx.x;
  for (int t = tid; t < 4 * DIM; t += 256)
    sx[t >> 7][t & 127] = x[(size_t)row0 * DIM + t];
  __syncthreads();
  const int r = tid >> 6;
  const int p = tid & 63;
  double aq = 0.0, ak = 0.0;
  for (int d = 0; d < DIM; ++d) {
    double xv = (double)sx[r][d];
    aq += xv * (double)Wq[d * PP + p];
    ak += xv * (double)Wk[d * PP + p];
  }
  aq += (double)bq[p];
  ak += (double)bk[p];
  const size_t o = ((size_t)row0 + r) * PP + p;
  Q[o] = (float)aq;
  K[o] = (float)ak;
}

// Per (batch, 64-row strip): compute scores vs all 2048 cols in 32-col tiles,
// maintain exact running top-64 via thresholded candidate buffer.
__global__ __launch_bounds__(256) void score_kernel(
    const float* __restrict__ Q, const float* __restrict__ K,
    const unsigned char* __restrict__ vmask,
    double* __restrict__ chunk_val, int* __restrict__ chunk_idx) {
  __shared__ float sQ[ROWS][PP + 1];   // +1 pad: conflict-free strided reads
  __shared__ float sK[CTILE][PP + 1];
  __shared__ double cval[CAPACITY];
  __shared__ int cidx[CAPACITY];
  __shared__ int rv[ROWS];
  __shared__ int cvld[CTILE];
  __shared__ double tval[KK];
  __shared__ int tidx[KK];
  __shared__ double swv[4];
  __shared__ int swi[4];
  __shared__ int swp[4];
  __shared__ int cnt;
  __shared__ double thresh;

  const int b = blockIdx.y;
  const int chunk = blockIdx.x;
  const int tid = threadIdx.x;
  const int r0 = chunk * ROWS;

  const float* Qb = Q + (((size_t)b * SL) + r0) * PP;
  for (int t = tid; t < ROWS * PP; t += 256)
    sQ[t >> 6][t & 63] = Qb[t];
  for (int t = tid; t < ROWS; t += 256) rv[t] = vmask[b * SL + r0 + t];
  if (tid == 0) { cnt = 0; thresh = -DBL_MAX; }
  __syncthreads();

  const int tx = tid & 15;   // 16 col-pairs
  const int ty = tid >> 4;   // 16 row-quads
  const int rbase = ty * 4;
  const int cbase = tx * 2;

  for (int c0 = 0; c0 < SL; c0 += CTILE) {
    const float* Kb = K + (((size_t)b * SL) + c0) * PP;
    for (int t = tid; t < CTILE * PP; t += 256)
      sK[t >> 6][t & 63] = Kb[t];
    for (int t = tid; t < CTILE; t += 256) cvld[t] = vmask[b * SL + c0 + t];
    __syncthreads();

    double a00 = 0, a01 = 0, a10 = 0, a11 = 0, a20 = 0, a21 = 0, a30 = 0, a31 = 0;
#pragma unroll 4
    for (int p = 0; p < PP; ++p) {
      double q0 = (double)sQ[rbase + 0][p];
      double q1 = (double)sQ[rbase + 1][p];
      double q2 = (double)sQ[rbase + 2][p];
      double q3 = (double)sQ[rbase + 3][p];
      double k0 = (double)sK[cbase + 0][p];
      double k1 = (double)sK[cbase + 1][p];
      a00 += q0 * k0; a01 += q0 * k1;
      a10 += q1 * k0; a11 += q1 * k1;
      a20 += q2 * k0; a21 += q2 * k1;
      a30 += q3 * k0; a31 += q3 * k1;
    }

    const double th = thresh;
    const double sc[4][2] = {{a00, a01}, {a10, a11}, {a20, a21}, {a30, a31}};
    for (int qq = 0; qq < 4; ++qq) {
      if (!rv[rbase + qq]) continue;
      for (int cc = 0; cc < 2; ++cc) {
        if (!cvld[cbase + cc]) continue;
        double s = sc[qq][cc] * 0.125;  // / sqrt(P), exact
        if (s >= th) {
          int pos = atomicAdd(&cnt, 1);  // bounded by CAPACITY by trigger below
          cval[pos] = s;
          cidx[pos] = (r0 + rbase + qq) * SL + (c0 + cbase + cc);
        }
      }
    }
    __syncthreads();
    if (cnt > CAPACITY - TILE_MAX) {  // next tile could overflow -> compact
      select_topk(cval, cidx, cnt, tval, tidx, swv, swi, swp);
      if (tid < KK) { cval[tid] = tval[tid]; cidx[tid] = tidx[tid]; }
      if (tid == 0) { cnt = KK; thresh = tval[KK - 1]; }
      __syncthreads();
    }
  }

  select_topk(cval, cidx, cnt, tval, tidx, swv, swi, swp);
  if (tid < KK) {
    const size_t o = (((size_t)b * NCHUNK) + chunk) * KK + tid;
    chunk_val[o] = tval[tid];
    chunk_idx[o] = tidx[tid];
  }
}

// One block per batch: merge 32*64 chunk candidates -> global top-64,
// softmax, write outputs (indices as floats, then weights).
__global__ __launch_bounds__(256) void merge_kernel(
    const double* __restrict__ chunk_val, const int* __restrict__ chunk_idx,
    float* __restrict__ out) {
  __shared__ double cval[NCHUNK * KK];
  __shared__ int cidx[NCHUNK * KK];
  __shared__ double tval[KK];
  __shared__ int tidx[KK];
  __shared__ double swv[4];
  __shared__ int swi[4];
  __shared__ int swp[4];
  __shared__ double ssum;
  const int b = blockIdx.x;
  const int tid = threadIdx.x;
  const int n = NCHUNK * KK;
  for (int t = tid; t < n; t += 256) {
    cval[t] = chunk_val[(size_t)b * n + t];
    cidx[t] = chunk_idx[(size_t)b * n + t];
  }
  __syncthreads();
  select_topk(cval, cidx, n, tval, tidx, swv, swi, swp);
  if (tid < 64) {
    double m = tval[0];
    double e = (tval[tid] == -DBL_MAX) ? 0.0 : exp(tval[tid] - m);
    double s = e;
    for (int off = 32; off > 0; off >>= 1) s += __shfl_down(s, off);
    if (tid == 0) ssum = (s > 0.0) ? s : 1.0;
  }
  __syncthreads();
  if (tid < 64) {
    double m = tval[0];
    double e = (tval[tid] == -DBL_MAX) ? 0.0 : exp(tval[tid] - m);
    double w = e / ssum;
    int ix = tidx[tid];
    int row = 0, col = 0;
    if (ix != INT_MAX) { row = ix / SL; col = ix % SL; } else { w = 0.0; }
    float* oidx = out;                               // (B, 64, 2)
    float* owt = out + (size_t)NB * KK * 2;          // (B, 64)
    oidx[((size_t)b * KK + tid) * 2 + 0] = (float)row;
    oidx[((size_t)b * KK + tid) * 2 + 1] = (float)col;
    owt[(size_t)b * KK + tid] = (float)w;
  }
}

}  // namespace

extern "C" void kernel_launch(void* const* d_in, const int* in_sizes, int n_in,
                              void* d_out, int out_size, void* d_ws, size_t ws_size,
                              hipStream_t stream) {
  const float* x = (const float*)d_in[0];
  const void* mask_raw = d_in[1];
  const float* Wq = (const float*)d_in[2];
  const float* bq = (const float*)d_in[3];
  const float* Wk = (const float*)d_in[4];
  const float* bk = (const float*)d_in[5];
  float* out = (float*)d_out;

  char* ws = (char*)d_ws;
  const size_t qk_elems = (size_t)NB * SL * PP;       // 1,048,576
  float* Q = (float*)ws;                              // 4 MB
  float* K = (float*)(ws + qk_elems * 4);             // 4 MB
  double* chunk_val = (double*)(ws + qk_elems * 8);   // 128 KB
  int* chunk_idx = (int*)(ws + qk_elems * 8 + (size_t)NB * NCHUNK * KK * 8);  // 64 KB
  unsigned char* vmask =
      (unsigned char*)(ws + qk_elems * 8 + (size_t)NB * NCHUNK * KK * 12);    // 16 KB

  mask_canon_kernel<<<1, 256, 0, stream>>>(mask_raw, vmask);
  proj_kernel<<<NB * SL / 4, 256, 0, stream>>>(x, Wq, bq, Wk, bk, Q, K);
  score_kernel<<<dim3(NCHUNK, NB), 256, 0, stream>>>(Q, K, vmask, chunk_val, chunk_idx);
  merge_kernel<<<NB, 256, 0, stream>>>(chunk_val, chunk_idx, out);
}

// Round 3
// 428.379 us; speedup vs baseline: 1.8886x; 1.8886x over previous
//
#include <hip/hip_runtime.h>
#include <float.h>
#include <limits.h>
#include <math.h>

namespace {

constexpr int NB = 8;
constexpr int SL = 2048;
constexpr int DIM = 128;
constexpr int PP = 64;
constexpr int KK = 64;
constexpr int ROWS = 64;            // compacted rows per strip
constexpr int CTILE = 64;           // compacted cols per tile
constexpr int NSTRIP = SL / ROWS;   // 32 strips (worst case all rows valid)
constexpr int CSPLIT = 4;           // col quarters
constexpr int NSLOT = NSTRIP * CSPLIT;  // 128 chunk slots per batch
constexpr int CAP = 2048;           // candidate buffer entries
constexpr float MARGIN = 4e-3f;     // >> 2x worst-case fp32 dot error (~1e-4)

__device__ __forceinline__ bool cgt64(double v1, int i1, double v2, int i2) {
  return (v1 > v2) || (v1 == v2 && i1 < i2);
}
__device__ __forceinline__ bool cgt32(float v1, int i1, float v2, int i2) {
  return (v1 > v2) || (v1 == v2 && i1 < i2);
}

// 256-thread exact top-KK select (fallback path), consumes winners in place.
__device__ void select_topk_block(double* cval, int* cidx, int n,
                                  double* ov, int* oi,
                                  double* swv, int* swi, double* swp) {
  const int tid = threadIdx.x;
  for (int k = 0; k < KK; ++k) {
    double bv = -DBL_MAX; int bi = INT_MAX; int bp = -1;
    for (int j = tid; j < n; j += 256) {
      if (cgt64(cval[j], cidx[j], bv, bi)) { bv = cval[j]; bi = cidx[j]; bp = j; }
    }
    for (int off = 32; off > 0; off >>= 1) {
      double v2 = __shfl_down(bv, off);
      int i2 = __shfl_down(bi, off);
      int p2 = __shfl_down(bp, off);
      if (cgt64(v2, i2, bv, bi)) { bv = v2; bi = i2; bp = p2; }
    }
    if ((tid & 63) == 0) { int w = tid >> 6; swv[w] = bv; swi[w] = bi; swp[w] = (double)bp; }
    __syncthreads();
    if (tid == 0) {
      double fv = swv[0]; int fi = swi[0]; int fp = (int)swp[0];
      for (int w = 1; w < 4; ++w)
        if (cgt64(swv[w], swi[w], fv, fi)) { fv = swv[w]; fi = swi[w]; fp = (int)swp[w]; }
      ov[k] = fv; oi[k] = fi;
      if (fp >= 0) { cval[fp] = -DBL_MAX; cidx[fp] = INT_MAX; }
    }
    __syncthreads();
  }
}

// Canonicalize mask (int32 words or raw bytes) + per-batch compaction of
// valid positions (ascending) into pos[b][..], count into cnt[b].
__global__ __launch_bounds__(256) void compact_kernel(
    const void* __restrict__ mask_raw, int* __restrict__ pos, int* __restrict__ cnt) {
  const int b = blockIdx.x;
  const int tid = threadIdx.x;
  const int lane = tid & 63, wid = tid >> 6;
  __shared__ int bytemode;
  __shared__ int wsum[4];
  if (tid == 0) bytemode = 0;
  __syncthreads();
  int local = 0;
  const unsigned char* allb = (const unsigned char*)mask_raw;
  for (int t = tid; t < NB * SL; t += 256)
    if ((t & 3) != 0 && allb[t] != 0) local = 1;
  if (local) atomicOr(&bytemode, 1);
  __syncthreads();
  int f[8]; int c = 0;
  const int base = tid * 8;
  if (bytemode) {
    const unsigned char* p = allb + (size_t)b * SL;
    for (int j = 0; j < 8; ++j) { f[j] = p[base + j] ? 1 : 0; c += f[j]; }
  } else {
    const int* p = (const int*)mask_raw + (size_t)b * SL;
    for (int j = 0; j < 8; ++j) { f[j] = p[base + j] ? 1 : 0; c += f[j]; }
  }
  int incl = c;
  for (int off = 1; off < 64; off <<= 1) {
    int t = __shfl_up(incl, off);
    if (lane >= off) incl += t;
  }
  if (lane == 63) wsum[wid] = incl;
  __syncthreads();
  int woff = 0;
  for (int w = 0; w < wid; ++w) woff += wsum[w];
  int k = woff + incl - c;
  for (int j = 0; j < 8; ++j)
    if (f[j]) pos[b * SL + (k++)] = base + j;
  if (tid == 255) cnt[b] = k;
}

// Q = x @ Wq + bq, K = x @ Wk + bk. Double accumulation, fp32 storage.
// UNCHANGED from R1 — Q/K bit patterns define the (verified absmax=0) ranking.
__global__ __launch_bounds__(256) void proj_kernel(
    const float* __restrict__ x,
    const float* __restrict__ Wq, const float* __restrict__ bq,
    const float* __restrict__ Wk, const float* __restrict__ bk,
    float* __restrict__ Q, float* __restrict__ K) {
  __shared__ float sx[4][DIM];
  const int row0 = blockIdx.x * 4;
  const int tid = threadIdx.x;
  for (int t = tid; t < 4 * DIM; t += 256)
    sx[t >> 7][t & 127] = x[(size_t)row0 * DIM + t];
  __syncthreads();
  const int r = tid >> 6;
  const int p = tid & 63;
  double aq = 0.0, ak = 0.0;
  for (int d = 0; d < DIM; ++d) {
    double xv = (double)sx[r][d];
    aq += xv * (double)Wq[d * PP + p];
    ak += xv * (double)Wk[d * PP + p];
  }
  aq += (double)bq[p];
  ak += (double)bk[p];
  const size_t o = ((size_t)row0 + r) * PP + p;
  Q[o] = (float)aq;
  K[o] = (float)ak;
}

// Safe initial threshold: per batch, 64th largest of the 256 per-thread maxima
// over the first-64-valid x first-64-valid score subset. Any subset 64th (or a
// lower bound of it) is <= global 64th, so T0 never excludes a true top-64.
__global__ __launch_bounds__(256) void t0_kernel(
    const float* __restrict__ Q, const float* __restrict__ K,
    const int* __restrict__ pos, const int* __restrict__ cnt,
    float* __restrict__ T0) {
  const int b = blockIdx.x;
  const int tid = threadIdx.x;
  const int lane = tid & 63;
  __shared__ float4 sq[64 * 16];
  __shared__ float4 sk[64 * 16];
  __shared__ float smax[256];
  const int nv = cnt[b];
  const int nr = nv < 64 ? nv : 64;
  for (int t = tid; t < 64 * 16; t += 256) {
    int row = t >> 4, p4 = t & 15;
    float4 qv = make_float4(0.f, 0.f, 0.f, 0.f), kv = qv;
    if (row < nr) {
      int g = pos[b * SL + row];
      qv = *(const float4*)(Q + ((size_t)b * SL + g) * PP + p4 * 4);
      kv = *(const float4*)(K + ((size_t)b * SL + g) * PP + p4 * 4);
    }
    sq[row * 16 + p4] = qv;
    sk[row * 16 + p4] = kv;
  }
  __syncthreads();
  const int r = tid >> 2;
  const int c0 = (tid & 3) * 16;
  float lmax = -FLT_MAX;
  if (r < nr) {
    for (int i = 0; i < 16; ++i) {
      int c = c0 + i;
      if (c >= nr) break;
      float s = 0.f;
      for (int p4 = 0; p4 < 16; ++p4) {
        float4 q = sq[r * 16 + p4];
        float4 kk = sk[c * 16 + p4];
        s = fmaf(q.x, kk.x, s); s = fmaf(q.y, kk.y, s);
        s = fmaf(q.z, kk.z, s); s = fmaf(q.w, kk.w, s);
      }
      s *= 0.125f;
      lmax = fmaxf(lmax, s);
    }
  }
  smax[tid] = lmax;
  __syncthreads();
  if (tid < 64) {
    float lv[4];
    for (int w = 0; w < 4; ++w) lv[w] = smax[lane + 64 * w];
    float t64 = -FLT_MAX;
    for (int k = 0; k < KK; ++k) {
      float bv = -FLT_MAX; int bid = INT_MAX;
      for (int w = 0; w < 4; ++w) {
        int id = lane * 4 + w;
        if (lv[w] > bv || (lv[w] == bv && id < bid)) { bv = lv[w]; bid = id; }
      }
      for (int off = 32; off > 0; off >>= 1) {
        float v2 = __shfl_down(bv, off); int i2 = __shfl_down(bid, off);
        if (v2 > bv || (v2 == bv && i2 < bid)) { bv = v2; bid = i2; }
      }
      bv = __shfl(bv, 0); bid = __shfl(bid, 0);
      if ((bid >> 2) == lane) lv[bid & 3] = -FLT_MAX;
      t64 = bv;
    }
    if (tid == 0) T0[b] = (t64 > -FLT_MAX) ? t64 - MARGIN : -FLT_MAX;
  }
}

// Per (batch, 64-compacted-row strip, col quarter): fp32 scores, thresholded
// candidate collection, fp64 refine of survivors, exact top-64 out.
__global__ __launch_bounds__(256, 3) void score_kernel(
    const float* __restrict__ Q, const float* __restrict__ K,
    const int* __restrict__ pos, const int* __restrict__ cnt,
    const float* __restrict__ T0,
    double* __restrict__ chunk_val, int* __restrict__ chunk_idx) {
  __shared__ float4 sQ4[16 * 64];   // [p4][row]           16 KB (aliased by rval later)
  __shared__ float4 sK4[16 * 64];   // [p4][col interlv]   16 KB
  __shared__ float cval[CAP];       // 8 KB
  __shared__ int cidx[CAP];         // 8 KB
  __shared__ int spos_r[ROWS];
  __shared__ int spos_c[CTILE];
  __shared__ double tvald[KK];
  __shared__ int tidxd[KK];
  __shared__ float tvalf[KK];
  __shared__ int tidxf[KK];
  __shared__ double swv[4]; __shared__ int swi[4]; __shared__ double swp[4];
  __shared__ float swvf[4]; __shared__ int swif[4];
  __shared__ int swsum[4];
  __shared__ int cnt_sh;
  __shared__ float thresh;

  const int b = blockIdx.z;
  const int strip = blockIdx.x;
  const int colq = blockIdx.y;
  const int tid = threadIdx.x;
  const int lane = tid & 63, wid = tid >> 6;
  const int nv = cnt[b];
  const int slot = b * NSLOT + strip * CSPLIT + colq;
  const int r0 = strip * ROWS;
  const int per = (nv + CSPLIT - 1) / CSPLIT;
  const int cbeg = colq * per;
  const int cend = min(cbeg + per, nv);
  if (r0 >= nv || cbeg >= cend) {
    if (tid < KK) {
      chunk_val[(size_t)slot * KK + tid] = -DBL_MAX;
      chunk_idx[(size_t)slot * KK + tid] = INT_MAX;
    }
    return;
  }
  const int nrows = min(ROWS, nv - r0);
  if (tid < ROWS) spos_r[tid] = (tid < nrows) ? pos[b * SL + r0 + tid] : 0;
  for (int t = tid; t < 16 * 64; t += 256) {
    int row = t >> 4, p4 = t & 15;
    float4 v = make_float4(0.f, 0.f, 0.f, 0.f);
    if (row < nrows) {
      int g = pos[b * SL + r0 + row];
      v = *(const float4*)(Q + ((size_t)b * SL + g) * PP + p4 * 4);
    }
    sQ4[p4 * 64 + row] = v;
  }
  if (tid == 0) { cnt_sh = 0; thresh = T0[b]; }
  __syncthreads();

  const int tx = tid & 31, ty = tid >> 5;

  for (int c0 = cbeg; c0 < cend; c0 += CTILE) {
    const int ncols = min(CTILE, cend - c0);
    if (tid < CTILE) spos_c[tid] = (tid < ncols) ? pos[b * SL + c0 + tid] : 0;
    for (int t = tid; t < 16 * 64; t += 256) {
      int col = t >> 4, p4 = t & 15;
      float4 v = make_float4(0.f, 0.f, 0.f, 0.f);
      if (col < ncols) {
        int g = pos[b * SL + c0 + col];
        v = *(const float4*)(K + ((size_t)b * SL + g) * PP + p4 * 4);
      }
      sK4[p4 * 64 + (col >> 1) + (col & 1) * 32] = v;  // even cols 0..31, odd 32..63
    }
    __syncthreads();

    float acc[8][2] = {};
#pragma unroll 4
    for (int p4 = 0; p4 < 16; ++p4) {
      float4 q[8], kk[2];
#pragma unroll
      for (int r = 0; r < 8; ++r) q[r] = sQ4[p4 * 64 + ty * 8 + r];
      kk[0] = sK4[p4 * 64 + tx];
      kk[1] = sK4[p4 * 64 + 32 + tx];
#pragma unroll
      for (int r = 0; r < 8; ++r) {
#pragma unroll
        for (int cc = 0; cc < 2; ++cc) {
          acc[r][cc] = fmaf(q[r].x, kk[cc].x, acc[r][cc]);
          acc[r][cc] = fmaf(q[r].y, kk[cc].y, acc[r][cc]);
          acc[r][cc] = fmaf(q[r].z, kk[cc].z, acc[r][cc]);
          acc[r][cc] = fmaf(q[r].w, kk[cc].w, acc[r][cc]);
        }
      }
    }

    // candidate emission with overflow-safe compaction
    for (int attempt = 0;; ++attempt) {
      __syncthreads();
      const float th = thresh;
      int nloc = 0;
#pragma unroll
      for (int r = 0; r < 8; ++r) {
        if (ty * 8 + r >= nrows) continue;
#pragma unroll
        for (int cc = 0; cc < 2; ++cc) {
          if (tx * 2 + cc >= ncols) continue;
          if (acc[r][cc] * 0.125f >= th) nloc++;
        }
      }
      int incl = nloc;
      for (int off = 1; off < 64; off <<= 1) {
        int t = __shfl_up(incl, off);
        if (lane >= off) incl += t;
      }
      if (lane == 63) swsum[wid] = incl;
      __syncthreads();
      const int total = swsum[0] + swsum[1] + swsum[2] + swsum[3];
      const int csnap = cnt_sh;
      __syncthreads();  // all reads of cnt_sh precede any push atomics
      if (csnap + total <= CAP || attempt >= 3) {
        int wbase = 0;
        if (lane == 63) wbase = atomicAdd(&cnt_sh, incl);
        wbase = __shfl(wbase, 63);
        int sl = wbase + (incl - nloc);
        for (int r = 0; r < 8; ++r) {
          int rr = ty * 8 + r;
          if (rr >= nrows) continue;
          for (int cc = 0; cc < 2; ++cc) {
            int ccc = tx * 2 + cc;
            if (ccc >= ncols) continue;
            float s = acc[r][cc] * 0.125f;
            if (s >= th) {
              if (sl < CAP) { cval[sl] = s; cidx[sl] = spos_r[rr] * SL + spos_c[ccc]; }
              sl++;
            }
          }
        }
        break;
      }
      // ---- compact: find 64th fp32, raise thresh, refilter buffer ----
      {
        __syncthreads();
        const int n = min(cnt_sh, CAP);
        float lv[8]; int li[8];
        for (int w = 0; w < 8; ++w) {
          int j = tid + w * 256;
          lv[w] = (j < n) ? cval[j] : -FLT_MAX;
          li[w] = (j < n) ? cidx[j] : INT_MAX;
        }
        __syncthreads();
        float t64 = -FLT_MAX;
        for (int k = 0; k < KK; ++k) {
          float bv = -FLT_MAX; int bi = INT_MAX;
          for (int w = 0; w < 8; ++w)
            if (cgt32(lv[w], li[w], bv, bi)) { bv = lv[w]; bi = li[w]; }
          for (int off = 32; off > 0; off >>= 1) {
            float v2 = __shfl_down(bv, off); int i2 = __shfl_down(bi, off);
            if (cgt32(v2, i2, bv, bi)) { bv = v2; bi = i2; }
          }
          if (lane == 0) { swvf[wid] = bv; swif[wid] = bi; }
          __syncthreads();
          float fv = swvf[0]; int fi = swif[0];
          for (int w = 1; w < 4; ++w)
            if (cgt32(swvf[w], swif[w], fv, fi)) { fv = swvf[w]; fi = swif[w]; }
          if (tid == 0) { tvalf[k] = fv; tidxf[k] = fi; }
          if (fi != INT_MAX)
            for (int w = 0; w < 8; ++w)
              if (li[w] == fi) { lv[w] = -FLT_MAX; li[w] = INT_MAX; }
          t64 = fv;
          __syncthreads();
        }
        if (tid == 0) {
          if (t64 > -FLT_MAX) thresh = t64 - MARGIN;
          cnt_sh = 0;
        }
        __syncthreads();
        if (tid < KK && tidxf[tid] != INT_MAX) {
          int p = atomicAdd(&cnt_sh, 1);
          cval[p] = tvalf[tid]; cidx[p] = tidxf[tid];
        }
        __syncthreads();
        const float th2 = thresh;
        int nloc2 = 0;
        for (int w = 0; w < 8; ++w)
          if (li[w] != INT_MAX && lv[w] >= th2) nloc2++;
        int incl2 = nloc2;
        for (int off = 1; off < 64; off <<= 1) {
          int t = __shfl_up(incl2, off);
          if (lane >= off) incl2 += t;
        }
        int wb = 0;
        if (lane == 63) wb = atomicAdd(&cnt_sh, incl2);
        wb = __shfl(wb, 63);
        int sl2 = wb + (incl2 - nloc2);
        for (int w = 0; w < 8; ++w)
          if (li[w] != INT_MAX && lv[w] >= th2) {
            if (sl2 < CAP) { cval[sl2] = lv[w]; cidx[sl2] = li[w]; }
            sl2++;
          }
        __syncthreads();
      }
    }
    __syncthreads();  // protect sK4/spos_c restage
  }

  // ---- fp64 refine of survivors + exact top-64 ----
  __syncthreads();
  const int n = min(cnt_sh, CAP);
  double* rval = (double*)sQ4;  // 2048 doubles = 16 KB alias (sQ4 dead now)
  __syncthreads();
  for (int j = tid; j < n; j += 256) {
    const int fi = cidx[j];
    const int orow = fi >> 11, ocol = fi & (SL - 1);
    const float* qr = Q + ((size_t)b * SL + orow) * PP;
    const float* kr = K + ((size_t)b * SL + ocol) * PP;
    double s = 0.0;
    for (int p = 0; p < PP; ++p) s = fma((double)qr[p], (double)kr[p], s);
    rval[j] = s * 0.125;
  }
  __syncthreads();
  if (n <= 512) {
    if (tid < 64) {
      double lw[8]; int li2[8];
      for (int w = 0; w < 8; ++w) {
        int j = lane + w * 64;
        lw[w] = (j < n) ? rval[j] : -DBL_MAX;
        li2[w] = (j < n) ? cidx[j] : INT_MAX;
      }
      for (int k = 0; k < KK; ++k) {
        double bv = -DBL_MAX; int bi = INT_MAX;
        for (int w = 0; w < 8; ++w)
          if (cgt64(lw[w], li2[w], bv, bi)) { bv = lw[w]; bi = li2[w]; }
        for (int off = 32; off > 0; off >>= 1) {
          double v2 = __shfl_down(bv, off); int i2 = __shfl_down(bi, off);
          if (cgt64(v2, i2, bv, bi)) { bv = v2; bi = i2; }
        }
        bv = __shfl(bv, 0); bi = __shfl(bi, 0);
        if (bi != INT_MAX)
          for (int w = 0; w < 8; ++w)
            if (li2[w] == bi) { lw[w] = -DBL_MAX; li2[w] = INT_MAX; }
        if (lane == 0) {
          chunk_val[(size_t)slot * KK + k] = bv;
          chunk_idx[(size_t)slot * KK + k] = bi;
        }
      }
    }
  } else {
    select_topk_block(rval, cidx, n, tvald, tidxd, swv, swi, swp);
    if (tid < KK) {
      chunk_val[(size_t)slot * KK + tid] = tvald[tid];
      chunk_idx[(size_t)slot * KK + tid] = tidxd[tid];
    }
  }
}

// One wave per batch: 128-way merge of sorted chunk lists -> global top-64,
// softmax, outputs.
__global__ __launch_bounds__(64) void merge_kernel(
    const double* __restrict__ chunk_val, const int* __restrict__ chunk_idx,
    float* __restrict__ out) {
  const int b = blockIdx.x;
  const int lane = threadIdx.x;
  const double* vb = chunk_val + (size_t)b * NSLOT * KK;
  const int* ib = chunk_idx + (size_t)b * NSLOT * KK;
  double curv[2]; int curi[2]; double nxtv[2]; int nxti[2]; int hp[2];
  for (int l = 0; l < 2; ++l) {
    const int list = lane * 2 + l;
    curv[l] = vb[list * KK + 0]; curi[l] = ib[list * KK + 0];
    nxtv[l] = vb[list * KK + 1]; nxti[l] = ib[list * KK + 1];
    hp[l] = 0;
  }
  double myv = -DBL_MAX; int myi = INT_MAX;
  for (int k = 0; k < KK; ++k) {
    double bv; int bi; int bg;
    if (cgt64(curv[0], curi[0], curv[1], curi[1])) { bv = curv[0]; bi = curi[0]; bg = lane * 2; }
    else { bv = curv[1]; bi = curi[1]; bg = lane * 2 + 1; }
    for (int off = 32; off > 0; off >>= 1) {
      double v2 = __shfl_down(bv, off);
      int i2 = __shfl_down(bi, off);
      int g2 = __shfl_down(bg, off);
      if (cgt64(v2, i2, bv, bi)) { bv = v2; bi = i2; bg = g2; }
    }
    bv = __shfl(bv, 0); bi = __shfl(bi, 0); bg = __shfl(bg, 0);
    if ((bg >> 1) == lane) {
      const int l = bg & 1;
      const int list = lane * 2 + l;
      hp[l]++;
      curv[l] = nxtv[l]; curi[l] = nxti[l];
      if (hp[l] + 1 < KK) { nxtv[l] = vb[list * KK + hp[l] + 1]; nxti[l] = ib[list * KK + hp[l] + 1]; }
      else { nxtv[l] = -DBL_MAX; nxti[l] = INT_MAX; }
    }
    if (lane == k) { myv = bv; myi = bi; }
  }
  const double m = __shfl(myv, 0);
  double e = (myi == INT_MAX || myv == -DBL_MAX) ? 0.0 : exp(myv - m);
  double s = e;
  for (int off = 32; off > 0; off >>= 1) s += __shfl_down(s, off);
  s = __shfl(s, 0);
  if (s <= 0.0) s = 1.0;
  const double w = e / s;
  int row = 0, col = 0;
  if (myi != INT_MAX) { row = myi >> 11; col = myi & (SL - 1); }
  float* oidx = out;
  float* owt = out + (size_t)NB * KK * 2;
  oidx[((size_t)b * KK + lane) * 2 + 0] = (float)row;
  oidx[((size_t)b * KK + lane) * 2 + 1] = (float)col;
  owt[(size_t)b * KK + lane] = (float)w;
}

}  // namespace

extern "C" void kernel_launch(void* const* d_in, const int* in_sizes, int n_in,
                              void* d_out, int out_size, void* d_ws, size_t ws_size,
                              hipStream_t stream) {
  const float* x = (const float*)d_in[0];
  const void* mask_raw = d_in[1];
  const float* Wq = (const float*)d_in[2];
  const float* bq = (const float*)d_in[3];
  const float* Wk = (const float*)d_in[4];
  const float* bk = (const float*)d_in[5];
  float* out = (float*)d_out;

  char* ws = (char*)d_ws;
  const size_t qk = (size_t)NB * SL * PP;  // 1,048,576 elems
  float* Q = (float*)ws;                                     // 4 MB
  float* K = (float*)(ws + qk * 4);                          // 4 MB
  double* chunk_val = (double*)(ws + qk * 8);                // 512 KB
  int* chunk_idx = (int*)(ws + qk * 8 + (size_t)NB * NSLOT * KK * 8);   // 256 KB
  int* pos = (int*)(ws + qk * 8 + (size_t)NB * NSLOT * KK * 12);        // 64 KB
  int* cntv = (int*)(ws + qk * 8 + (size_t)NB * NSLOT * KK * 12 + (size_t)NB * SL * 4);
  float* T0 = (float*)(ws + qk * 8 + (size_t)NB * NSLOT * KK * 12 + (size_t)NB * SL * 4 + 64);

  compact_kernel<<<NB, 256, 0, stream>>>(mask_raw, pos, cntv);
  proj_kernel<<<NB * SL / 4, 256, 0, stream>>>(x, Wq, bq, Wk, bk, Q, K);
  t0_kernel<<<NB, 256, 0, stream>>>(Q, K, pos, cntv, T0);
  score_kernel<<<dim3(NSTRIP, CSPLIT, NB), 256, 0, stream>>>(Q, K, pos, cntv, T0,
                                                             chunk_val, chunk_idx);
  merge_kernel<<<NB, 64, 0, stream>>>(chunk_val, chunk_idx, out);
}